// Round 6
// baseline (190.410 us; speedup 1.0000x reference)
//
#include <hip/hip_runtime.h>

// GroupNorm(32) -> phi 1x1 -> soft-VQ softmax vs codebook -> wz 1x1 + residual. fp32 I/O.
// x:(10,64,128,128), mb:(64,512), phi_w/wz_w:(64,64). B=10, C=64, HW=16384, K=512.
//
// R15 = R11 base (proven 64.9us main; 32x32 R14 regressed to 73.5 + HBM churn) with
// the mbY staging removed:
//  - ay Y-frags read DIRECT from global (L2) per wave, 8x16B per chunk, hoisted to
//    the chunk top so their ~400cy latency hides under the score-MFMA+exp2 phase
//    (unlike R10, there is now work to overlap; and they don't join the barrier
//    drain critical path).
//  - Staged chunk halves to 8KB (mbA only) -> lighter vmcnt(0) drain per barrier.
//  - LDS 51.2KB -> 34.8KB -> 4 blocks/CU = 16 waves/CU (+33% residency),
//    __launch_bounds__(256,4) (est VGPR ~116 <= 128).
//  - Everything else byte-identical to R11: 16x16 MFMA, exp2/PSC + v_perm bf16 pack,
//    stride-72 E rows, per-wave parity dbuf E, 8-way-split atomic GN stats.
//
// ws (ushort):
//  [0    ..32768) mbA  scores A-frags  (((cc*4+u)*2+s)*64+lane)*8+j = mb[s*32+q*8+j][(cc*4+u)*16+m]
//  [32768..65536) mbY  Y A-frags       (((cc*2+s2)*4+mt)*64+lane)*8+j = mb[mt*16+m][cc*64+s2*32+q*8+j]
//  [65536..69632) phiA ((mt*2+s)*64+lane)*8+j = phi_w[mt*16+m][s*32+q*8+j]
//  [69632..73728) wzA  same for wz_w
//  float view at ushort 73728 (statf): [0..320) sum[b*32+g], [320..640) sumsq (atomic)

#define HWN 16384
#define CCH 64
#define PSC 0.18033688011112042f   // 0.125 * log2(e)

using short8 = __attribute__((ext_vector_type(8))) short;
using f32x4  = __attribute__((ext_vector_type(4))) float;

__device__ __forceinline__ ushort f2bf(float f) {
    union { float f; unsigned int i; } v; v.f = f;
    return (ushort)((v.i + 0x8000u) >> 16);   // round-half-up
}
__device__ __forceinline__ unsigned int pk2(float a, float b) {
    union { float f; unsigned int i; } va, vb; va.f = a; vb.f = b;
    return __builtin_amdgcn_perm(vb.i + 0x8000u, va.i + 0x8000u, 0x07060302u);
}

// blocks [0, nstat): GroupNorm partial sums, 8 parts per (b,g), atomicAdd into statf.
// blocks [nstat, nstat+288): weight prep gathers.
__global__ __launch_bounds__(256) void prep_stats_kernel(
    const float* __restrict__ x, const float* __restrict__ mb,
    const float* __restrict__ phiw, const float* __restrict__ wzw,
    ushort* __restrict__ ws, int nstat)
{
    if (blockIdx.x >= nstat) {
        int i = (blockIdx.x - nstat) * 256 + threadIdx.x;   // 0..73727
        int j = i & 7, lane = (i >> 3) & 63, m = lane & 15, q = lane >> 4;
        if (i < 32768) {
            int t = i >> 9, tile = t >> 1, s = t & 1;
            ws[i] = f2bf(mb[(s * 32 + q * 8 + j) * 512 + tile * 16 + m]);
        } else if (i < 65536) {
            int t = (i - 32768) >> 9;
            int mt = t & 3, u2 = t >> 2, s2 = u2 & 1, cc = u2 >> 1;
            ws[i] = f2bf(mb[(mt * 16 + m) * 512 + cc * 64 + s2 * 32 + q * 8 + j]);
        } else if (i < 69632) {
            int t = (i - 65536) >> 9, mt = t >> 1, s = t & 1;
            ws[i] = f2bf(phiw[(mt * 16 + m) * 64 + s * 32 + q * 8 + j]);
        } else {
            int t = (i - 69632) >> 9, mt = t >> 1, s = t & 1;
            ws[i] = f2bf(wzw[(mt * 16 + m) * 64 + s * 32 + q * 8 + j]);
        }
        return;
    }
    float* statf = (float*)(ws + 73728);
    int blk  = blockIdx.x;            // b*256 + g*8 + part
    int b    = blk >> 8;
    int g    = (blk >> 3) & 31;
    int part = blk & 7;
    const float4* b4 = (const float4*)(x + (size_t)b * CCH * HWN + (size_t)(g * 2) * HWN) + part * 1024;
    float s = 0.f, s2 = 0.f;
    for (int i = threadIdx.x; i < 1024; i += 256) {
        float4 u = b4[i];
        s  += (u.x + u.y) + (u.z + u.w);
        s2 += (u.x*u.x + u.y*u.y) + (u.z*u.z + u.w*u.w);
    }
    for (int off = 32; off > 0; off >>= 1) {
        s  += __shfl_down(s, off);
        s2 += __shfl_down(s2, off);
    }
    __shared__ float rs[4], rs2[4];
    int wave = threadIdx.x >> 6, lane = threadIdx.x & 63;
    if (lane == 0) { rs[wave] = s; rs2[wave] = s2; }
    __syncthreads();
    if (threadIdx.x == 0) {
        atomicAdd(&statf[b * 32 + g],       rs[0] + rs[1] + rs[2] + rs[3]);
        atomicAdd(&statf[320 + b * 32 + g], rs2[0] + rs2[1] + rs2[2] + rs2[3]);
    }
}

// Stage one 8KB mbA frag chunk into LDS, split across 4 waves (2 x 1KB insts each).
// mbA chunk cc = ws bytes [cc*8192, +8192). LDS dest linear (uniform base + lane*16).
__device__ __forceinline__ void stage_chunk(const ushort* ws, ushort* fg,
                                            int cc, int wv, int lane) {
    const char* g = (const char*)ws + cc * 8192 + wv * 2048 + lane * 16;
    char* l = (char*)fg + wv * 2048 + lane * 16;
#pragma unroll
    for (int k = 0; k < 2; ++k)
        __builtin_amdgcn_global_load_lds(
            (const __attribute__((address_space(1))) unsigned int*)(g + k * 1024),
            (__attribute__((address_space(3))) unsigned int*)(l + k * 1024),
            16, 0, 0);
}

__global__ __launch_bounds__(256, 4) void main_mfma(
    const float* __restrict__ x, const ushort* __restrict__ ws,
    const float* __restrict__ phib, const float* __restrict__ gnw,
    const float* __restrict__ gnb, const float* __restrict__ wzb,
    float* __restrict__ out)
{
    const int lane = threadIdx.x & 63, wv = threadIdx.x >> 6;
    const int m = lane & 15, q = lane >> 4;
    const int blk = blockIdx.x;                       // 2560 blocks, 64 tokens each
    const int b   = blk >> 8;                         // 256 blocks per image
    const int hw0 = ((blk & 255) << 6) + (wv << 4);   // this wave's 16 tokens

    const ushort* mbY  = ws + 32768;
    const ushort* phiA = ws + 65536;
    const ushort* wzA  = ws + 69632;
    const float*  statf = (const float*)(ws + 73728);

    __shared__ ushort Fg[2][4096];                    // mbA staging: 2 x 8KB
    __shared__ ushort Sl[4][2][16 * 72];              // E: [wave][parity], 18.4KB
    ushort* Ebuf[2] = { &Sl[wv][0][0], &Sl[wv][1][0] };
    ushort* E0 = Ebuf[0];

    const float* xb = x + (size_t)b * CCH * HWN;

    // prologue: kick off chunk-0 frag staging; its latency hides under stage 1.
    stage_chunk(ws, &Fg[0][0], 0, wv, lane);

    // ---- stage 1: x -> GroupNorm (finalize from atomic sums) -> bf16 B-frags ----
    short8 bx[2];
#pragma unroll
    for (int s = 0; s < 2; ++s) {
        const int cbase = s * 32 + q * 8;
        f32x4 sm4 = *(const f32x4*)(statf + b * 32 + (cbase >> 1));
        f32x4 sq4 = *(const f32x4*)(statf + 320 + b * 32 + (cbase >> 1));
        f32x4 mu4, rs4;
#pragma unroll
        for (int r = 0; r < 4; ++r) {
            mu4[r] = sm4[r] * (1.f / 32768.f);
            float var = sq4[r] * (1.f / 32768.f) - mu4[r] * mu4[r];
            rs4[r] = rsqrtf(var + 1e-6f);
        }
        f32x4 gwv0 = *(const f32x4*)(gnw + cbase), gwv1 = *(const f32x4*)(gnw + cbase + 4);
        f32x4 gbv0 = *(const f32x4*)(gnb + cbase), gbv1 = *(const f32x4*)(gnb + cbase + 4);
#pragma unroll
        for (int j = 0; j < 8; ++j) {
            float v  = xb[(size_t)(cbase + j) * HWN + hw0 + m];
            float gw = (j < 4) ? gwv0[j & 3] : gwv1[j & 3];
            float gb = (j < 4) ? gbv0[j & 3] : gbv1[j & 3];
            float xn = (v - mu4[j >> 1]) * rs4[j >> 1] * gw + gb;
            bx[s][j] = (short)f2bf(xn);
        }
    }

    // ---- P^T = phi_w * xn ; store scaled by PSC so softmax exp is bare exp2 ----
#pragma unroll
    for (int mt = 0; mt < 4; ++mt) {
        f32x4 a = (f32x4){0.f,0.f,0.f,0.f};
#pragma unroll
        for (int s = 0; s < 2; ++s) {
            short8 ap = *(const short8*)(phiA + (((mt * 2 + s) * 64 + lane) << 3));
            a = __builtin_amdgcn_mfma_f32_16x16x32_bf16(ap, bx[s], a, 0, 0, 0);
        }
        f32x4 pb = *(const f32x4*)(phib + mt * 16 + q * 4);
        *(uint2*)(E0 + m * 72 + mt * 16 + q * 4) =
            make_uint2(pk2((a[0]+pb[0])*PSC, (a[1]+pb[1])*PSC),
                       pk2((a[2]+pb[2])*PSC, (a[3]+pb[3])*PSC));
    }

    // hoist this lane's token-row of P (chunk-invariant score B-frags)
    short8 bp[2];
#pragma unroll
    for (int s = 0; s < 2; ++s)
        bp[s] = *(const short8*)(E0 + m * 72 + s * 32 + q * 8);

    // chunk-0 frags must be resident before anyone reads them
    __syncthreads();   // implicit vmcnt(0)+lgkmcnt(0) drain

    // ---- streaming softmax + Y over 8 chunks of 64 codebook entries ----
    f32x4 accY[4];
#pragma unroll
    for (int mt = 0; mt < 4; ++mt) accY[mt] = (f32x4){0.f,0.f,0.f,0.f};
    float lsum = 0.f;

    for (int cc = 0; cc < 8; ++cc) {
        if (cc < 7) stage_chunk(ws, &Fg[(cc + 1) & 1][0], cc + 1, wv, lane);

        // hoist this chunk's Y A-frags from global (L2); latency hides under the
        // score/exp phase below. 8 x 16B/lane, ~32 VGPRs transient.
        short8 ayr[2][4];
#pragma unroll
        for (int s2 = 0; s2 < 2; ++s2)
#pragma unroll
            for (int mt = 0; mt < 4; ++mt)
                ayr[s2][mt] = *(const short8*)(mbY + ((((cc * 2 + s2) * 4 + mt) * 64 + lane) << 3));

        const ushort* fA = &Fg[cc & 1][0];      // mbA chunk: 4096 ushorts
        ushort* Eb = Ebuf[cc & 1];
#pragma unroll
        for (int u = 0; u < 4; ++u) {
            short8 am0 = *(const short8*)(fA + (((u * 2 + 0) * 64 + lane) << 3));
            short8 am1 = *(const short8*)(fA + (((u * 2 + 1) * 64 + lane) << 3));
            f32x4 sa = (f32x4){0.f,0.f,0.f,0.f};
            sa = __builtin_amdgcn_mfma_f32_16x16x32_bf16(am0, bp[0], sa, 0, 0, 0);
            sa = __builtin_amdgcn_mfma_f32_16x16x32_bf16(am1, bp[1], sa, 0, 0, 0);
            float e0 = __builtin_exp2f(sa[0]), e1 = __builtin_exp2f(sa[1]);
            float e2 = __builtin_exp2f(sa[2]), e3 = __builtin_exp2f(sa[3]);
            lsum += (e0 + e1) + (e2 + e3);
            *(uint2*)(Eb + m * 72 + u * 16 + q * 4) =
                make_uint2(pk2(e0, e1), pk2(e2, e3));
        }
#pragma unroll
        for (int s2 = 0; s2 < 2; ++s2) {
            short8 be = *(const short8*)(Eb + m * 72 + s2 * 32 + q * 8);
#pragma unroll
            for (int mt = 0; mt < 4; ++mt)
                accY[mt] = __builtin_amdgcn_mfma_f32_16x16x32_bf16(ayr[s2][mt], be, accY[mt], 0, 0, 0);
        }
        // next-chunk staging must land and all waves must be done with fA
        __syncthreads();   // implicit vmcnt(0) drain (covered by this chunk's compute)
    }

    // softmax denominator: lane's C-column IS its token; reduce across q
    float l = lsum;
    l += __shfl_xor(l, 16);
    l += __shfl_xor(l, 32);
    const float linv = 1.f / l;

    // ---- Y -> LDS (B-layout), then Out^T = wz * Y ----
#pragma unroll
    for (int mt = 0; mt < 4; ++mt)
        *(uint2*)(E0 + m * 72 + mt * 16 + q * 4) =
            make_uint2(pk2(accY[mt][0], accY[mt][1]), pk2(accY[mt][2], accY[mt][3]));

    short8 by[2];
#pragma unroll
    for (int s = 0; s < 2; ++s)
        by[s] = *(const short8*)(E0 + m * 72 + s * 32 + q * 8);

    float* ob = out + (size_t)b * CCH * HWN;
#pragma unroll
    for (int mt = 0; mt < 4; ++mt) {
        f32x4 c = (f32x4){0.f,0.f,0.f,0.f};
#pragma unroll
        for (int s = 0; s < 2; ++s) {
            short8 aw = *(const short8*)(wzA + (((mt * 2 + s) * 64 + lane) << 3));
            c = __builtin_amdgcn_mfma_f32_16x16x32_bf16(aw, by[s], c, 0, 0, 0);
        }
        f32x4 wb = *(const f32x4*)(wzb + mt * 16 + q * 4);
#pragma unroll
        for (int r = 0; r < 4; ++r) {
            int o = mt * 16 + q * 4 + r;
            size_t base = (size_t)o * HWN + hw0 + m;
            ob[base] = c[r] * linv + wb[r] + xb[base];
        }
    }
}

extern "C" void kernel_launch(void* const* d_in, const int* in_sizes, int n_in,
                              void* d_out, int out_size, void* d_ws, size_t ws_size,
                              hipStream_t stream) {
    const float* x    = (const float*)d_in[0];
    const float* mb   = (const float*)d_in[1];
    const float* phiw = (const float*)d_in[2];
    const float* phib = (const float*)d_in[3];
    const float* gnw  = (const float*)d_in[4];
    const float* gnb  = (const float*)d_in[5];
    const float* wzw  = (const float*)d_in[6];
    const float* wzb  = (const float*)d_in[7];

    const int B = in_sizes[0] / (CCH * HWN);  // 10
    const int nstat = B * 256;                // 8 partial blocks per (b,g)

    // zero the atomic-sum region (float idx 36864..37504 of ws)
    hipMemsetAsync((char*)d_ws + 36864 * 4, 0, 640 * 4, stream);
    prep_stats_kernel<<<nstat + 288, 256, 0, stream>>>(x, mb, phiw, wzw,
                                                       (ushort*)d_ws, nstat);
    main_mfma<<<B * 256, 256, 0, stream>>>(x, (const ushort*)d_ws,
                                           phib, gnw, gnb, wzb, (float*)d_out);
}

// Round 7
// 168.949 us; speedup vs baseline: 1.1270x; 1.1270x over previous
//
#include <hip/hip_runtime.h>

// GroupNorm(32) -> phi 1x1 -> soft-VQ softmax vs codebook -> wz 1x1 + residual. fp32 I/O.
// x:(10,64,128,128), mb:(64,512), phi_w/wz_w:(64,64). B=10, C=64, HW=16384, K=512.
//
// R16 = R15 with the spill fixed. R15's only defect: __launch_bounds__(256,4) forced
// VGPR_Count=64 (needs ~116 with the hoisted ayr frags) -> scratch spill every chunk,
// visible as +66MB FETCH / +110MB WRITE of symmetric round-trip traffic and main
// 99.7us. Occupancy DID rise to 37% as designed. Fix: (256,2) -- compiler lands
// ~116 VGPR <= 128, which still allows 4 waves/SIMD; LDS 34.8KB allows 4 blocks/CU.
//
// Structure (R15 = R11 base + mbY staging removed):
//  - ay Y-frags read DIRECT from global (L2) per chunk, hoisted to the chunk top so
//    their latency hides under the score-MFMA+exp2 phase.
//  - Staged chunk is mbA only (8KB) -> lighter vmcnt(0) drain per barrier.
//  - LDS 34.8KB (Fg 16K + E 18.4K) -> 4 blocks/CU = 16 waves/CU.
//  - 16x16 MFMA, exp2/PSC + v_perm bf16 pack, stride-72 E rows, per-wave parity
//    dbuf E, 8-way-split atomic GN stats.
//
// ws (ushort):
//  [0    ..32768) mbA  scores A-frags  (((cc*4+u)*2+s)*64+lane)*8+j = mb[s*32+q*8+j][(cc*4+u)*16+m]
//  [32768..65536) mbY  Y A-frags       (((cc*2+s2)*4+mt)*64+lane)*8+j = mb[mt*16+m][cc*64+s2*32+q*8+j]
//  [65536..69632) phiA ((mt*2+s)*64+lane)*8+j = phi_w[mt*16+m][s*32+q*8+j]
//  [69632..73728) wzA  same for wz_w
//  float view at ushort 73728 (statf): [0..320) sum[b*32+g], [320..640) sumsq (atomic)

#define HWN 16384
#define CCH 64
#define PSC 0.18033688011112042f   // 0.125 * log2(e)

using short8 = __attribute__((ext_vector_type(8))) short;
using f32x4  = __attribute__((ext_vector_type(4))) float;

__device__ __forceinline__ ushort f2bf(float f) {
    union { float f; unsigned int i; } v; v.f = f;
    return (ushort)((v.i + 0x8000u) >> 16);   // round-half-up
}
__device__ __forceinline__ unsigned int pk2(float a, float b) {
    union { float f; unsigned int i; } va, vb; va.f = a; vb.f = b;
    return __builtin_amdgcn_perm(vb.i + 0x8000u, va.i + 0x8000u, 0x07060302u);
}

// blocks [0, nstat): GroupNorm partial sums, 8 parts per (b,g), atomicAdd into statf.
// blocks [nstat, nstat+288): weight prep gathers.
__global__ __launch_bounds__(256) void prep_stats_kernel(
    const float* __restrict__ x, const float* __restrict__ mb,
    const float* __restrict__ phiw, const float* __restrict__ wzw,
    ushort* __restrict__ ws, int nstat)
{
    if (blockIdx.x >= nstat) {
        int i = (blockIdx.x - nstat) * 256 + threadIdx.x;   // 0..73727
        int j = i & 7, lane = (i >> 3) & 63, m = lane & 15, q = lane >> 4;
        if (i < 32768) {
            int t = i >> 9, tile = t >> 1, s = t & 1;
            ws[i] = f2bf(mb[(s * 32 + q * 8 + j) * 512 + tile * 16 + m]);
        } else if (i < 65536) {
            int t = (i - 32768) >> 9;
            int mt = t & 3, u2 = t >> 2, s2 = u2 & 1, cc = u2 >> 1;
            ws[i] = f2bf(mb[(mt * 16 + m) * 512 + cc * 64 + s2 * 32 + q * 8 + j]);
        } else if (i < 69632) {
            int t = (i - 65536) >> 9, mt = t >> 1, s = t & 1;
            ws[i] = f2bf(phiw[(mt * 16 + m) * 64 + s * 32 + q * 8 + j]);
        } else {
            int t = (i - 69632) >> 9, mt = t >> 1, s = t & 1;
            ws[i] = f2bf(wzw[(mt * 16 + m) * 64 + s * 32 + q * 8 + j]);
        }
        return;
    }
    float* statf = (float*)(ws + 73728);
    int blk  = blockIdx.x;            // b*256 + g*8 + part
    int b    = blk >> 8;
    int g    = (blk >> 3) & 31;
    int part = blk & 7;
    const float4* b4 = (const float4*)(x + (size_t)b * CCH * HWN + (size_t)(g * 2) * HWN) + part * 1024;
    float s = 0.f, s2 = 0.f;
    for (int i = threadIdx.x; i < 1024; i += 256) {
        float4 u = b4[i];
        s  += (u.x + u.y) + (u.z + u.w);
        s2 += (u.x*u.x + u.y*u.y) + (u.z*u.z + u.w*u.w);
    }
    for (int off = 32; off > 0; off >>= 1) {
        s  += __shfl_down(s, off);
        s2 += __shfl_down(s2, off);
    }
    __shared__ float rs[4], rs2[4];
    int wave = threadIdx.x >> 6, lane = threadIdx.x & 63;
    if (lane == 0) { rs[wave] = s; rs2[wave] = s2; }
    __syncthreads();
    if (threadIdx.x == 0) {
        atomicAdd(&statf[b * 32 + g],       rs[0] + rs[1] + rs[2] + rs[3]);
        atomicAdd(&statf[320 + b * 32 + g], rs2[0] + rs2[1] + rs2[2] + rs2[3]);
    }
}

// Stage one 8KB mbA frag chunk into LDS, split across 4 waves (2 x 1KB insts each).
// mbA chunk cc = ws bytes [cc*8192, +8192). LDS dest linear (uniform base + lane*16).
__device__ __forceinline__ void stage_chunk(const ushort* ws, ushort* fg,
                                            int cc, int wv, int lane) {
    const char* g = (const char*)ws + cc * 8192 + wv * 2048 + lane * 16;
    char* l = (char*)fg + wv * 2048 + lane * 16;
#pragma unroll
    for (int k = 0; k < 2; ++k)
        __builtin_amdgcn_global_load_lds(
            (const __attribute__((address_space(1))) unsigned int*)(g + k * 1024),
            (__attribute__((address_space(3))) unsigned int*)(l + k * 1024),
            16, 0, 0);
}

__global__ __launch_bounds__(256, 2) void main_mfma(
    const float* __restrict__ x, const ushort* __restrict__ ws,
    const float* __restrict__ phib, const float* __restrict__ gnw,
    const float* __restrict__ gnb, const float* __restrict__ wzb,
    float* __restrict__ out)
{
    const int lane = threadIdx.x & 63, wv = threadIdx.x >> 6;
    const int m = lane & 15, q = lane >> 4;
    const int blk = blockIdx.x;                       // 2560 blocks, 64 tokens each
    const int b   = blk >> 8;                         // 256 blocks per image
    const int hw0 = ((blk & 255) << 6) + (wv << 4);   // this wave's 16 tokens

    const ushort* mbY  = ws + 32768;
    const ushort* phiA = ws + 65536;
    const ushort* wzA  = ws + 69632;
    const float*  statf = (const float*)(ws + 73728);

    __shared__ ushort Fg[2][4096];                    // mbA staging: 2 x 8KB
    __shared__ ushort Sl[4][2][16 * 72];              // E: [wave][parity], 18.4KB
    ushort* Ebuf[2] = { &Sl[wv][0][0], &Sl[wv][1][0] };
    ushort* E0 = Ebuf[0];

    const float* xb = x + (size_t)b * CCH * HWN;

    // prologue: kick off chunk-0 frag staging; its latency hides under stage 1.
    stage_chunk(ws, &Fg[0][0], 0, wv, lane);

    // ---- stage 1: x -> GroupNorm (finalize from atomic sums) -> bf16 B-frags ----
    short8 bx[2];
#pragma unroll
    for (int s = 0; s < 2; ++s) {
        const int cbase = s * 32 + q * 8;
        f32x4 sm4 = *(const f32x4*)(statf + b * 32 + (cbase >> 1));
        f32x4 sq4 = *(const f32x4*)(statf + 320 + b * 32 + (cbase >> 1));
        f32x4 mu4, rs4;
#pragma unroll
        for (int r = 0; r < 4; ++r) {
            mu4[r] = sm4[r] * (1.f / 32768.f);
            float var = sq4[r] * (1.f / 32768.f) - mu4[r] * mu4[r];
            rs4[r] = rsqrtf(var + 1e-6f);
        }
        f32x4 gwv0 = *(const f32x4*)(gnw + cbase), gwv1 = *(const f32x4*)(gnw + cbase + 4);
        f32x4 gbv0 = *(const f32x4*)(gnb + cbase), gbv1 = *(const f32x4*)(gnb + cbase + 4);
#pragma unroll
        for (int j = 0; j < 8; ++j) {
            float v  = xb[(size_t)(cbase + j) * HWN + hw0 + m];
            float gw = (j < 4) ? gwv0[j & 3] : gwv1[j & 3];
            float gb = (j < 4) ? gbv0[j & 3] : gbv1[j & 3];
            float xn = (v - mu4[j >> 1]) * rs4[j >> 1] * gw + gb;
            bx[s][j] = (short)f2bf(xn);
        }
    }

    // ---- P^T = phi_w * xn ; store scaled by PSC so softmax exp is bare exp2 ----
#pragma unroll
    for (int mt = 0; mt < 4; ++mt) {
        f32x4 a = (f32x4){0.f,0.f,0.f,0.f};
#pragma unroll
        for (int s = 0; s < 2; ++s) {
            short8 ap = *(const short8*)(phiA + (((mt * 2 + s) * 64 + lane) << 3));
            a = __builtin_amdgcn_mfma_f32_16x16x32_bf16(ap, bx[s], a, 0, 0, 0);
        }
        f32x4 pb = *(const f32x4*)(phib + mt * 16 + q * 4);
        *(uint2*)(E0 + m * 72 + mt * 16 + q * 4) =
            make_uint2(pk2((a[0]+pb[0])*PSC, (a[1]+pb[1])*PSC),
                       pk2((a[2]+pb[2])*PSC, (a[3]+pb[3])*PSC));
    }

    // hoist this lane's token-row of P (chunk-invariant score B-frags)
    short8 bp[2];
#pragma unroll
    for (int s = 0; s < 2; ++s)
        bp[s] = *(const short8*)(E0 + m * 72 + s * 32 + q * 8);

    // chunk-0 frags must be resident before anyone reads them
    __syncthreads();   // implicit vmcnt(0)+lgkmcnt(0) drain

    // ---- streaming softmax + Y over 8 chunks of 64 codebook entries ----
    f32x4 accY[4];
#pragma unroll
    for (int mt = 0; mt < 4; ++mt) accY[mt] = (f32x4){0.f,0.f,0.f,0.f};
    float lsum = 0.f;

    for (int cc = 0; cc < 8; ++cc) {
        if (cc < 7) stage_chunk(ws, &Fg[(cc + 1) & 1][0], cc + 1, wv, lane);

        // hoist this chunk's Y A-frags from global (L2); latency hides under the
        // score/exp phase below. 8 x 16B/lane, ~32 VGPRs transient.
        short8 ayr[2][4];
#pragma unroll
        for (int s2 = 0; s2 < 2; ++s2)
#pragma unroll
            for (int mt = 0; mt < 4; ++mt)
                ayr[s2][mt] = *(const short8*)(mbY + ((((cc * 2 + s2) * 4 + mt) * 64 + lane) << 3));

        const ushort* fA = &Fg[cc & 1][0];      // mbA chunk: 4096 ushorts
        ushort* Eb = Ebuf[cc & 1];
#pragma unroll
        for (int u = 0; u < 4; ++u) {
            short8 am0 = *(const short8*)(fA + (((u * 2 + 0) * 64 + lane) << 3));
            short8 am1 = *(const short8*)(fA + (((u * 2 + 1) * 64 + lane) << 3));
            f32x4 sa = (f32x4){0.f,0.f,0.f,0.f};
            sa = __builtin_amdgcn_mfma_f32_16x16x32_bf16(am0, bp[0], sa, 0, 0, 0);
            sa = __builtin_amdgcn_mfma_f32_16x16x32_bf16(am1, bp[1], sa, 0, 0, 0);
            float e0 = __builtin_exp2f(sa[0]), e1 = __builtin_exp2f(sa[1]);
            float e2 = __builtin_exp2f(sa[2]), e3 = __builtin_exp2f(sa[3]);
            lsum += (e0 + e1) + (e2 + e3);
            *(uint2*)(Eb + m * 72 + u * 16 + q * 4) =
                make_uint2(pk2(e0, e1), pk2(e2, e3));
        }
#pragma unroll
        for (int s2 = 0; s2 < 2; ++s2) {
            short8 be = *(const short8*)(Eb + m * 72 + s2 * 32 + q * 8);
#pragma unroll
            for (int mt = 0; mt < 4; ++mt)
                accY[mt] = __builtin_amdgcn_mfma_f32_16x16x32_bf16(ayr[s2][mt], be, accY[mt], 0, 0, 0);
        }
        // next-chunk staging must land and all waves must be done with fA
        __syncthreads();   // implicit vmcnt(0) drain (covered by this chunk's compute)
    }

    // softmax denominator: lane's C-column IS its token; reduce across q
    float l = lsum;
    l += __shfl_xor(l, 16);
    l += __shfl_xor(l, 32);
    const float linv = 1.f / l;

    // ---- Y -> LDS (B-layout), then Out^T = wz * Y ----
#pragma unroll
    for (int mt = 0; mt < 4; ++mt)
        *(uint2*)(E0 + m * 72 + mt * 16 + q * 4) =
            make_uint2(pk2(accY[mt][0], accY[mt][1]), pk2(accY[mt][2], accY[mt][3]));

    short8 by[2];
#pragma unroll
    for (int s = 0; s < 2; ++s)
        by[s] = *(const short8*)(E0 + m * 72 + s * 32 + q * 8);

    float* ob = out + (size_t)b * CCH * HWN;
#pragma unroll
    for (int mt = 0; mt < 4; ++mt) {
        f32x4 c = (f32x4){0.f,0.f,0.f,0.f};
#pragma unroll
        for (int s = 0; s < 2; ++s) {
            short8 aw = *(const short8*)(wzA + (((mt * 2 + s) * 64 + lane) << 3));
            c = __builtin_amdgcn_mfma_f32_16x16x32_bf16(aw, by[s], c, 0, 0, 0);
        }
        f32x4 wb = *(const f32x4*)(wzb + mt * 16 + q * 4);
#pragma unroll
        for (int r = 0; r < 4; ++r) {
            int o = mt * 16 + q * 4 + r;
            size_t base = (size_t)o * HWN + hw0 + m;
            ob[base] = c[r] * linv + wb[r] + xb[base];
        }
    }
}

extern "C" void kernel_launch(void* const* d_in, const int* in_sizes, int n_in,
                              void* d_out, int out_size, void* d_ws, size_t ws_size,
                              hipStream_t stream) {
    const float* x    = (const float*)d_in[0];
    const float* mb   = (const float*)d_in[1];
    const float* phiw = (const float*)d_in[2];
    const float* phib = (const float*)d_in[3];
    const float* gnw  = (const float*)d_in[4];
    const float* gnb  = (const float*)d_in[5];
    const float* wzw  = (const float*)d_in[6];
    const float* wzb  = (const float*)d_in[7];

    const int B = in_sizes[0] / (CCH * HWN);  // 10
    const int nstat = B * 256;                // 8 partial blocks per (b,g)

    // zero the atomic-sum region (float idx 36864..37504 of ws)
    hipMemsetAsync((char*)d_ws + 36864 * 4, 0, 640 * 4, stream);
    prep_stats_kernel<<<nstat + 288, 256, 0, stream>>>(x, mb, phiw, wzw,
                                                       (ushort*)d_ws, nstat);
    main_mfma<<<B * 256, 256, 0, stream>>>(x, (const ushort*)d_ws,
                                           phib, gnw, gnb, wzb, (float*)d_out);
}

// Round 8
// 151.351 us; speedup vs baseline: 1.2581x; 1.1163x over previous
//
#include <hip/hip_runtime.h>

// GroupNorm(32) -> phi 1x1 -> soft-VQ softmax vs codebook -> wz 1x1 + residual. fp32 I/O.
// x:(10,64,128,128), mb:(64,512), phi_w/wz_w:(64,64). B=10, C=64, HW=16384, K=512.
//
// R17 = R11 structure (both mbA+mbY staged -- R15/R16 proved direct frag loads get
// sunk by the allocator and serialize) with the barrier drain removed:
//  - 16 half-chunks of 32 codebook entries (8KB: mbA 4K + mbY 4K). Same ws layout,
//    same accumulation order -> bit-identical output.
//  - TRIPLE-buffered staging (Fg 3x8KB=24KB): stage(hc+2) issued at top of chunk hc,
//    end-of-chunk is s_waitcnt vmcnt(2) + raw s_barrier (NOT __syncthreads -- no
//    vmcnt(0) drain). stage(hc+1) gets a 2-chunk window; newest stage stays in
//    flight across the barrier (T4 counted-vmcnt). Ledger: only stage loads make
//    vmem inside the loop (GN/phi loads complete pre-loop; vmcnt is in-order).
//  - E scratch: stride-40 rows (32 entries + 8 pad), [4][2][16*40] = 10KB; the two
//    parity buffers double as channel-halves for the 64-ch P/Y roundtrips.
//  - LDS 34.8KB -> 4 blocks/CU = 16 waves/CU (VGPR ~90 keeps 4 waves/SIMD legal).
//
// ws (ushort): identical to R11 (mbA/mbY linear in half-chunk order):
//  [0    ..32768) mbA  (((hc*2+u)*2+s)*64+lane)*8+j = mb[s*32+q*8+j][(hc*2+u)*16+m]
//  [32768..65536) mbY  ((hc*4+mt)*64+lane)*8+j      = mb[mt*16+m][hc*32+q*8+j]
//  [65536..69632) phiA ((mt*2+s)*64+lane)*8+j = phi_w[mt*16+m][s*32+q*8+j]
//  [69632..73728) wzA  same for wz_w
//  float view at ushort 73728 (statf): [0..320) sum[b*32+g], [320..640) sumsq (atomic)

#define HWN 16384
#define CCH 64
#define PSC 0.18033688011112042f   // 0.125 * log2(e)
#define ETS 40                     // E row stride (ushorts): 32 entries + 8 pad, 16B-mult

using short8 = __attribute__((ext_vector_type(8))) short;
using f32x4  = __attribute__((ext_vector_type(4))) float;

__device__ __forceinline__ ushort f2bf(float f) {
    union { float f; unsigned int i; } v; v.f = f;
    return (ushort)((v.i + 0x8000u) >> 16);   // round-half-up
}
__device__ __forceinline__ unsigned int pk2(float a, float b) {
    union { float f; unsigned int i; } va, vb; va.f = a; vb.f = b;
    return __builtin_amdgcn_perm(vb.i + 0x8000u, va.i + 0x8000u, 0x07060302u);
}

// blocks [0, nstat): GroupNorm partial sums, 8 parts per (b,g), atomicAdd into statf.
// blocks [nstat, nstat+288): weight prep gathers. (unchanged from R11)
__global__ __launch_bounds__(256) void prep_stats_kernel(
    const float* __restrict__ x, const float* __restrict__ mb,
    const float* __restrict__ phiw, const float* __restrict__ wzw,
    ushort* __restrict__ ws, int nstat)
{
    if (blockIdx.x >= nstat) {
        int i = (blockIdx.x - nstat) * 256 + threadIdx.x;   // 0..73727
        int j = i & 7, lane = (i >> 3) & 63, m = lane & 15, q = lane >> 4;
        if (i < 32768) {
            int t = i >> 9, tile = t >> 1, s = t & 1;
            ws[i] = f2bf(mb[(s * 32 + q * 8 + j) * 512 + tile * 16 + m]);
        } else if (i < 65536) {
            int t = (i - 32768) >> 9;
            int mt = t & 3, u2 = t >> 2, s2 = u2 & 1, cc = u2 >> 1;
            ws[i] = f2bf(mb[(mt * 16 + m) * 512 + cc * 64 + s2 * 32 + q * 8 + j]);
        } else if (i < 69632) {
            int t = (i - 65536) >> 9, mt = t >> 1, s = t & 1;
            ws[i] = f2bf(phiw[(mt * 16 + m) * 64 + s * 32 + q * 8 + j]);
        } else {
            int t = (i - 69632) >> 9, mt = t >> 1, s = t & 1;
            ws[i] = f2bf(wzw[(mt * 16 + m) * 64 + s * 32 + q * 8 + j]);
        }
        return;
    }
    float* statf = (float*)(ws + 73728);
    int blk  = blockIdx.x;            // b*256 + g*8 + part
    int b    = blk >> 8;
    int g    = (blk >> 3) & 31;
    int part = blk & 7;
    const float4* b4 = (const float4*)(x + (size_t)b * CCH * HWN + (size_t)(g * 2) * HWN) + part * 1024;
    float s = 0.f, s2 = 0.f;
    for (int i = threadIdx.x; i < 1024; i += 256) {
        float4 u = b4[i];
        s  += (u.x + u.y) + (u.z + u.w);
        s2 += (u.x*u.x + u.y*u.y) + (u.z*u.z + u.w*u.w);
    }
    for (int off = 32; off > 0; off >>= 1) {
        s  += __shfl_down(s, off);
        s2 += __shfl_down(s2, off);
    }
    __shared__ float rs[4], rs2[4];
    int wave = threadIdx.x >> 6, lane = threadIdx.x & 63;
    if (lane == 0) { rs[wave] = s; rs2[wave] = s2; }
    __syncthreads();
    if (threadIdx.x == 0) {
        atomicAdd(&statf[b * 32 + g],       rs[0] + rs[1] + rs[2] + rs[3]);
        atomicAdd(&statf[320 + b * 32 + g], rs2[0] + rs2[1] + rs2[2] + rs2[3]);
    }
}

// Stage one 8KB half-chunk (mbA 4KB + mbY 4KB) into an LDS buffer, 2KB per wave.
// waves 0,1 -> mbA halves; waves 2,3 -> mbY halves. Dest linear (base + lane*16).
__device__ __forceinline__ void stage_chunk(const ushort* ws, ushort* fg,
                                            int hc, int wv, int lane) {
    const char* g = (const char*)ws + (wv >= 2 ? 65536 : 0) + hc * 4096
                    + (wv & 1) * 2048 + lane * 16;
    char* l = (char*)fg + (wv >= 2 ? 4096 : 0) + (wv & 1) * 2048 + lane * 16;
#pragma unroll
    for (int k = 0; k < 2; ++k)
        __builtin_amdgcn_global_load_lds(
            (const __attribute__((address_space(1))) unsigned int*)(g + k * 1024),
            (__attribute__((address_space(3))) unsigned int*)(l + k * 1024),
            16, 0, 0);
}

__global__ __launch_bounds__(256, 2) void main_mfma(
    const float* __restrict__ x, const ushort* __restrict__ ws,
    const float* __restrict__ phib, const float* __restrict__ gnw,
    const float* __restrict__ gnb, const float* __restrict__ wzb,
    float* __restrict__ out)
{
    const int lane = threadIdx.x & 63, wv = threadIdx.x >> 6;
    const int m = lane & 15, q = lane >> 4;
    const int blk = blockIdx.x;                       // 2560 blocks, 64 tokens each
    const int b   = blk >> 8;                         // 256 blocks per image
    const int hw0 = ((blk & 255) << 6) + (wv << 4);   // this wave's 16 tokens

    const ushort* phiA = ws + 65536;
    const ushort* wzA  = ws + 69632;
    const float*  statf = (const float*)(ws + 73728);

    __shared__ ushort Fg[3][4096];                    // staging: 3 x 8KB
    __shared__ ushort Sl[4][2][16 * ETS];             // E: [wave][parity], 10KB
    ushort* Ebuf[2] = { &Sl[wv][0][0], &Sl[wv][1][0] };

    const float* xb = x + (size_t)b * CCH * HWN;

    // prologue: stage chunks 0 and 1 (latency hides under GN+phi).
    stage_chunk(ws, &Fg[0][0], 0, wv, lane);
    stage_chunk(ws, &Fg[1][0], 1, wv, lane);

    // ---- stage 1: x -> GroupNorm (finalize from atomic sums) -> bf16 B-frags ----
    short8 bx[2];
#pragma unroll
    for (int s = 0; s < 2; ++s) {
        const int cbase = s * 32 + q * 8;
        f32x4 sm4 = *(const f32x4*)(statf + b * 32 + (cbase >> 1));
        f32x4 sq4 = *(const f32x4*)(statf + 320 + b * 32 + (cbase >> 1));
        f32x4 mu4, rs4;
#pragma unroll
        for (int r = 0; r < 4; ++r) {
            mu4[r] = sm4[r] * (1.f / 32768.f);
            float var = sq4[r] * (1.f / 32768.f) - mu4[r] * mu4[r];
            rs4[r] = rsqrtf(var + 1e-6f);
        }
        f32x4 gwv0 = *(const f32x4*)(gnw + cbase), gwv1 = *(const f32x4*)(gnw + cbase + 4);
        f32x4 gbv0 = *(const f32x4*)(gnb + cbase), gbv1 = *(const f32x4*)(gnb + cbase + 4);
#pragma unroll
        for (int j = 0; j < 8; ++j) {
            float v  = xb[(size_t)(cbase + j) * HWN + hw0 + m];
            float gw = (j < 4) ? gwv0[j & 3] : gwv1[j & 3];
            float gb = (j < 4) ? gbv0[j & 3] : gbv1[j & 3];
            float xn = (v - mu4[j >> 1]) * rs4[j >> 1] * gw + gb;
            bx[s][j] = (short)f2bf(xn);
        }
    }

    // ---- P^T = phi_w * xn ; channels 0..31 -> Ebuf[0], 32..63 -> Ebuf[1] ----
#pragma unroll
    for (int mt = 0; mt < 4; ++mt) {
        f32x4 a = (f32x4){0.f,0.f,0.f,0.f};
#pragma unroll
        for (int s = 0; s < 2; ++s) {
            short8 ap = *(const short8*)(phiA + (((mt * 2 + s) * 64 + lane) << 3));
            a = __builtin_amdgcn_mfma_f32_16x16x32_bf16(ap, bx[s], a, 0, 0, 0);
        }
        f32x4 pb = *(const f32x4*)(phib + mt * 16 + q * 4);
        *(uint2*)(Ebuf[mt >> 1] + m * ETS + (mt & 1) * 16 + q * 4) =
            make_uint2(pk2((a[0]+pb[0])*PSC, (a[1]+pb[1])*PSC),
                       pk2((a[2]+pb[2])*PSC, (a[3]+pb[3])*PSC));
    }

    // hoist this lane's token-row of P (chunk-invariant score B-frags)
    short8 bp[2];
#pragma unroll
    for (int s = 0; s < 2; ++s)
        bp[s] = *(const short8*)(Ebuf[s] + m * ETS + q * 8);

    // chunk-0 staged data must be resident (in-order vmcnt: the GN/phi load waits
    // above already forced st0/st1 completion; this is belt-and-braces, not a drain).
    asm volatile("s_waitcnt vmcnt(2)" ::: "memory");
    __builtin_amdgcn_s_barrier();

    // ---- streaming softmax + Y over 16 half-chunks of 32 codebook entries ----
    f32x4 accY[4];
#pragma unroll
    for (int mt = 0; mt < 4; ++mt) accY[mt] = (f32x4){0.f,0.f,0.f,0.f};
    float lsum = 0.f;

    ushort* f0 = &Fg[0][0];    // read buffer for current chunk
    ushort* f1 = &Fg[1][0];    // next
    ushort* f2 = &Fg[2][0];    // stage target

    for (int hc = 0; hc < 16; ++hc) {
        if (hc < 14) stage_chunk(ws, f2, hc + 2, wv, lane);
        const ushort* fA = f0;            // mbA half-chunk: 2048 ushorts
        const ushort* fY = f0 + 2048;     // mbY half-chunk: 2048 ushorts
        ushort* Eb = Ebuf[hc & 1];
#pragma unroll
        for (int u = 0; u < 2; ++u) {
            short8 am0 = *(const short8*)(fA + (((u * 2 + 0) * 64 + lane) << 3));
            short8 am1 = *(const short8*)(fA + (((u * 2 + 1) * 64 + lane) << 3));
            f32x4 sa = (f32x4){0.f,0.f,0.f,0.f};
            sa = __builtin_amdgcn_mfma_f32_16x16x32_bf16(am0, bp[0], sa, 0, 0, 0);
            sa = __builtin_amdgcn_mfma_f32_16x16x32_bf16(am1, bp[1], sa, 0, 0, 0);
            float e0 = __builtin_exp2f(sa[0]), e1 = __builtin_exp2f(sa[1]);
            float e2 = __builtin_exp2f(sa[2]), e3 = __builtin_exp2f(sa[3]);
            lsum += (e0 + e1) + (e2 + e3);
            *(uint2*)(Eb + m * ETS + u * 16 + q * 4) =
                make_uint2(pk2(e0, e1), pk2(e2, e3));
        }
        {
            short8 be = *(const short8*)(Eb + m * ETS + q * 8);
#pragma unroll
            for (int mt = 0; mt < 4; ++mt) {
                short8 ay = *(const short8*)(fY + (((mt * 64 + lane)) << 3));
                accY[mt] = __builtin_amdgcn_mfma_f32_16x16x32_bf16(ay, be, accY[mt], 0, 0, 0);
            }
        }
        // counted wait: stage(hc+1) must be resident for the next chunk; the
        // newest stage (hc+2, 2 loads) stays in flight across the barrier.
        if (hc < 14) {
            asm volatile("s_waitcnt vmcnt(2)" ::: "memory");
            __builtin_amdgcn_s_barrier();
        } else if (hc == 14) {
            asm volatile("s_waitcnt vmcnt(0)" ::: "memory");
            __builtin_amdgcn_s_barrier();
        }
        ushort* t = f0; f0 = f1; f1 = f2; f2 = t;   // rotate triple buffer
    }

    // softmax denominator: lane's C-column IS its token; reduce across q
    float l = lsum;
    l += __shfl_xor(l, 16);
    l += __shfl_xor(l, 32);
    const float linv = 1.f / l;

    // ---- Y -> E (channels 0..31 -> Ebuf[0], 32..63 -> Ebuf[1]), then wz GEMM ----
#pragma unroll
    for (int mt = 0; mt < 4; ++mt)
        *(uint2*)(Ebuf[mt >> 1] + m * ETS + (mt & 1) * 16 + q * 4) =
            make_uint2(pk2(accY[mt][0], accY[mt][1]), pk2(accY[mt][2], accY[mt][3]));

    short8 by[2];
#pragma unroll
    for (int s = 0; s < 2; ++s)
        by[s] = *(const short8*)(Ebuf[s] + m * ETS + q * 8);

    float* ob = out + (size_t)b * CCH * HWN;
#pragma unroll
    for (int mt = 0; mt < 4; ++mt) {
        f32x4 c = (f32x4){0.f,0.f,0.f,0.f};
#pragma unroll
        for (int s = 0; s < 2; ++s) {
            short8 aw = *(const short8*)(wzA + (((mt * 2 + s) * 64 + lane) << 3));
            c = __builtin_amdgcn_mfma_f32_16x16x32_bf16(aw, by[s], c, 0, 0, 0);
        }
        f32x4 wb = *(const f32x4*)(wzb + mt * 16 + q * 4);
#pragma unroll
        for (int r = 0; r < 4; ++r) {
            int o = mt * 16 + q * 4 + r;
            size_t base = (size_t)o * HWN + hw0 + m;
            ob[base] = c[r] * linv + wb[r] + xb[base];
        }
    }
}

extern "C" void kernel_launch(void* const* d_in, const int* in_sizes, int n_in,
                              void* d_out, int out_size, void* d_ws, size_t ws_size,
                              hipStream_t stream) {
    const float* x    = (const float*)d_in[0];
    const float* mb   = (const float*)d_in[1];
    const float* phiw = (const float*)d_in[2];
    const float* phib = (const float*)d_in[3];
    const float* gnw  = (const float*)d_in[4];
    const float* gnb  = (const float*)d_in[5];
    const float* wzw  = (const float*)d_in[6];
    const float* wzb  = (const float*)d_in[7];

    const int B = in_sizes[0] / (CCH * HWN);  // 10
    const int nstat = B * 256;                // 8 partial blocks per (b,g)

    // zero the atomic-sum region (float idx 36864..37504 of ws)
    hipMemsetAsync((char*)d_ws + 36864 * 4, 0, 640 * 4, stream);
    prep_stats_kernel<<<nstat + 288, 256, 0, stream>>>(x, mb, phiw, wzw,
                                                       (ushort*)d_ws, nstat);
    main_mfma<<<B * 256, 256, 0, stream>>>(x, (const ushort*)d_ws,
                                           phib, gnw, gnb, wzb, (float*)d_out);
}